// Round 1
// baseline (345.642 us; speedup 1.0000x reference)
//
#include <hip/hip_runtime.h>

#define HH 512
#define WW 512
#define NBATCH 16
#define NBINS 512   // 511 real shells + 1 overflow (dropped)

// ---------------------------------------------------------------------------
// 512-point radix-2 Stockham FFT in LDS. 256 threads, 1 butterfly each per
// stage, 9 stages, ping-pong between a and b. Returns pointer to the buffer
// holding the result (natural order). Forward DFT (exp(-2*pi*i*k*n/N)).
// ---------------------------------------------------------------------------
__device__ __forceinline__ float2* fft512(float2* a, float2* b, int tid) {
    float2* src = a;
    float2* dst = b;
#pragma unroll
    for (int s = 0; s < 9; ++s) {
        const int m = 1 << s;          // current "m" (output half-stride)
        const int j = tid >> s;        // twiddle index, j in [0, 256>>s)
        float2 c0 = src[tid];
        float2 c1 = src[tid + 256];
        float sx = c0.x + c1.x, sy = c0.y + c1.y;
        float dx = c0.x - c1.x, dy = c0.y - c1.y;
        // w = exp(-i * pi * j / l), l = 256 >> s
        float ang = -3.14159265358979323846f * (float)j / (float)(256 >> s);
        float sn, cs;
        __sincosf(ang, &sn, &cs);
        int idx = tid + (j << s);      // = k + 2*j*m
        dst[idx]     = make_float2(sx, sy);
        dst[idx + m] = make_float2(cs * dx - sn * dy, cs * dy + sn * dx);
        __syncthreads();
        float2* tmp = src; src = dst; dst = tmp;
    }
    return src;   // buffer written by the last stage
}

// ---------------------------------------------------------------------------
// Row pass: build field (f==0: t, f==1: z - t) for one row, FFT it, store.
// grid.x = CB*2*512 (local field fl = local_b*2 + f, row h), block = 256.
// ---------------------------------------------------------------------------
__global__ void row_fft_kernel(const float2* __restrict__ z,
                               const float2* __restrict__ t,
                               float2* __restrict__ fields,
                               int b0) {
    __shared__ float2 bufA[512];
    __shared__ float2 bufB[512];
    const int tid = threadIdx.x;
    const int bid = blockIdx.x;
    const int h  = bid & 511;
    const int fl = bid >> 9;
    const int f  = fl & 1;
    const int b  = b0 + (fl >> 1);

    const float2* tp = t + ((size_t)(b * HH + h)) * WW;
    const float2* zp = z + ((size_t)(b * HH + h)) * WW;
    for (int i = tid; i < 512; i += 256) {
        float2 tv = tp[i];
        float2 v;
        if (f == 0) {
            v = tv;
        } else {
            float2 zv = zp[i];
            v = make_float2(zv.x - tv.x, zv.y - tv.y);
        }
        bufA[i] = v;
    }
    __syncthreads();
    float2* res = fft512(bufA, bufB, tid);
    float2* outp = fields + ((size_t)fl * HH + h) * WW;
    for (int i = tid; i < 512; i += 256) outp[i] = res[i];
}

// ---------------------------------------------------------------------------
// Column pass: FFT one column of one field, write |X|^2.
// grid.x = CB*2*512 (field fl, column c), block = 256.
// ---------------------------------------------------------------------------
__global__ void col_fft_mag_kernel(const float2* __restrict__ fields,
                                   float* __restrict__ mags) {
    __shared__ float2 bufA[512];
    __shared__ float2 bufB[512];
    const int tid = threadIdx.x;
    const int bid = blockIdx.x;
    const int c  = bid & 511;
    const int fl = bid >> 9;

    const float2* src = fields + (size_t)fl * HH * WW + c;
    for (int i = tid; i < 512; i += 256) bufA[i] = src[(size_t)i * WW];
    __syncthreads();
    float2* res = fft512(bufA, bufB, tid);
    float* outp = mags + (size_t)fl * HH * WW + c;
    for (int i = tid; i < 512; i += 256) {
        float2 v = res[i];
        outp[(size_t)i * WW] = v.x * v.x + v.y * v.y;
    }
}

// ---------------------------------------------------------------------------
// Binning: per-block LDS histogram over a 8192-pixel slice of one field,
// then one global atomicAdd per bin. bins layout: [f][b][bin], f=0 norm(t),
// f=1 err(z-t). grid.x = CB*2*32, block = 256.
// ---------------------------------------------------------------------------
__global__ void bin_kernel(const float* __restrict__ mags,
                           float* __restrict__ bins,
                           int b0) {
    __shared__ float lb[NBINS];
    const int tid  = threadIdx.x;
    const int bid  = blockIdx.x;
    const int part = bid & 31;
    const int fl   = bid >> 5;
    const int f    = fl & 1;
    const int b    = b0 + (fl >> 1);

    lb[tid] = 0.f;
    lb[tid + 256] = 0.f;
    __syncthreads();

    const float* mp = mags + (size_t)fl * HH * WW + (size_t)part * 8192;
#pragma unroll 4
    for (int i = 0; i < 32; ++i) {
        int p = part * 8192 + i * 256 + tid;
        int r = p >> 9;
        int c = p & 511;
        float fa = (float)(r - 256) * (1.0f / 256.0f);
        float fb = (float)(c - 256) * (1.0f / 256.0f);
        float e = fa * fa + fb * fb;               // exact in fp32
        int bin = (int)(sqrt((double)e) * 511.0);  // searchsorted-right equiv
        bin = min(bin, 511);
        atomicAdd(&lb[bin], mp[i * 256 + tid]);
    }
    __syncthreads();
    float* gb = bins + ((size_t)f * NBATCH + b) * NBINS;
    atomicAdd(&gb[tid],       lb[tid]);
    atomicAdd(&gb[tid + 256], lb[tid + 256]);
}

// ---------------------------------------------------------------------------
// Final: loss = mean_b sum_{k<511} es[b][k] / max(ns[b][k], 1e-8)
// ---------------------------------------------------------------------------
__global__ void loss_kernel(const float* __restrict__ bins,
                            float* __restrict__ outp) {
    __shared__ float red[256];
    const int tid = threadIdx.x;
    float acc = 0.f;
    for (int b = 0; b < NBATCH; ++b) {
        const float* ns = bins + (size_t)b * NBINS;             // f = 0
        const float* es = bins + (size_t)(NBATCH + b) * NBINS;  // f = 1
        for (int k = tid; k < 511; k += 256)
            acc += es[k] / fmaxf(ns[k], 1e-8f);
    }
    red[tid] = acc;
    __syncthreads();
    for (int s = 128; s > 0; s >>= 1) {
        if (tid < s) red[tid] += red[tid + s];
        __syncthreads();
    }
    if (tid == 0) outp[0] = red[0] / (float)NBATCH;
}

// ---------------------------------------------------------------------------
extern "C" void kernel_launch(void* const* d_in, const int* in_sizes, int n_in,
                              void* d_out, int out_size, void* d_ws, size_t ws_size,
                              hipStream_t stream) {
    const float2* z = (const float2*)d_in[0];
    const float2* t = (const float2*)d_in[1];
    float* outp = (float*)d_out;

    const size_t binsBytes = (size_t)2 * NBATCH * NBINS * sizeof(float);  // 64 KiB
    const size_t fpb = (size_t)2 * HH * WW * sizeof(float2);  // 4 MiB / batch (2 fields)
    const size_t mpb = (size_t)2 * HH * WW * sizeof(float);   // 2 MiB / batch

    // Largest power-of-two batch chunk that fits the workspace.
    int CB = 16;
    while (CB > 1 && binsBytes + (size_t)CB * (fpb + mpb) > ws_size) CB >>= 1;

    float*  bins   = (float*)d_ws;
    float2* fields = (float2*)((char*)d_ws + binsBytes);
    float*  mags   = (float*)((char*)d_ws + binsBytes + (size_t)CB * fpb);

    hipMemsetAsync(d_ws, 0, binsBytes, stream);

    for (int b0 = 0; b0 < NBATCH; b0 += CB) {
        row_fft_kernel<<<CB * 2 * 512, 256, 0, stream>>>(z, t, fields, b0);
        col_fft_mag_kernel<<<CB * 2 * 512, 256, 0, stream>>>(fields, mags);
        bin_kernel<<<CB * 2 * 32, 256, 0, stream>>>(mags, bins, b0);
    }
    loss_kernel<<<1, 256, 0, stream>>>(bins, outp);
}

// Round 2
// 220.511 us; speedup vs baseline: 1.5675x; 1.5675x over previous
//
#include <hip/hip_runtime.h>

#define HH 512
#define WW 512
#define NBATCH 16
#define NBINS 512   // 511 real shells + 1 overflow (dropped)
#define NC 8        // columns per block in the column pass

// ---------------------------------------------------------------------------
// 512-point radix-2 Stockham FFT in LDS. 256 threads, 1 butterfly each per
// stage, 9 stages, ping-pong between a and b. Returns pointer to the buffer
// holding the result (natural order). Forward DFT (exp(-2*pi*i*k*n/N)).
// ---------------------------------------------------------------------------
__device__ __forceinline__ float2* fft512(float2* a, float2* b, int tid) {
    float2* src = a;
    float2* dst = b;
#pragma unroll
    for (int s = 0; s < 9; ++s) {
        const int m = 1 << s;          // current "m" (output half-stride)
        const int j = tid >> s;        // twiddle index, j in [0, 256>>s)
        float2 c0 = src[tid];
        float2 c1 = src[tid + 256];
        float sx = c0.x + c1.x, sy = c0.y + c1.y;
        float dx = c0.x - c1.x, dy = c0.y - c1.y;
        // w = exp(-i * pi * j / l), l = 256 >> s
        float ang = -3.14159265358979323846f * (float)j / (float)(256 >> s);
        float sn, cs;
        __sincosf(ang, &sn, &cs);
        int idx = tid + (j << s);      // = k + 2*j*m
        dst[idx]     = make_float2(sx, sy);
        dst[idx + m] = make_float2(cs * dx - sn * dy, cs * dy + sn * dx);
        __syncthreads();
        float2* tmp = src; src = dst; dst = tmp;
    }
    return src;   // buffer written by the last stage (always b: 9 swaps)
}

// ---------------------------------------------------------------------------
// Row pass: one block per (batch, row). Builds BOTH fields (t and z - t),
// FFTs each, stores to fields[2b] / fields[2b+1]. float4 loads/stores.
// grid.x = CB*512, block = 256.
// ---------------------------------------------------------------------------
__global__ __launch_bounds__(256)
void row_fft_kernel(const float4* __restrict__ z4,
                    const float4* __restrict__ t4,
                    float2* __restrict__ fields,
                    int b0) {
    __shared__ float2 bufA[512];
    __shared__ float2 bufB[512];
    const int tid = threadIdx.x;
    const int bid = blockIdx.x;
    const int h  = bid & 511;
    const int lb = bid >> 9;          // local batch index
    const int b  = b0 + lb;

    const float4* tp = t4 + (size_t)(b * HH + h) * (WW / 2);
    const float4* zp = z4 + (size_t)(b * HH + h) * (WW / 2);
    float4 tv = tp[tid];              // pixels 2*tid, 2*tid+1
    float4 zv = zp[tid];

    // field 0: t
    ((float4*)bufA)[tid] = tv;
    __syncthreads();
    float2* r = fft512(bufA, bufB, tid);
    float2* out0 = fields + ((size_t)(lb * 2) * HH + h) * WW;
    ((float4*)out0)[tid] = ((float4*)r)[tid];

    // field 1: z - t  (bufA reads of fft #1 all completed by its last sync;
    // the sync after refill also orders our bufB reads above vs stage-0 writes)
    ((float4*)bufA)[tid] = make_float4(zv.x - tv.x, zv.y - tv.y,
                                       zv.z - tv.z, zv.w - tv.w);
    __syncthreads();
    r = fft512(bufA, bufB, tid);
    float2* out1 = fields + ((size_t)(lb * 2 + 1) * HH + h) * WW;
    ((float4*)out1)[tid] = ((float4*)r)[tid];
}

// ---------------------------------------------------------------------------
// Column pass: one block per (field, 8-column group). Coalesced 64B row-
// segment loads into LDS [col][row], 8 parallel 512-pt FFTs (32 threads per
// column), last stage fused with |X|^2 + radial binning into an LDS
// histogram (aliased into the free ping-pong buffer), then one global
// atomicAdd per bin. grid.x = CB*2*64, block = 256.
// ---------------------------------------------------------------------------
__global__ __launch_bounds__(256)
void col_fft_bin_kernel(const float2* __restrict__ fields,
                        float* __restrict__ bins,
                        int b0) {
    __shared__ float2 bufA[NC * 512];
    __shared__ float2 bufB[NC * 512];
    const int tid = threadIdx.x;
    const int bid = blockIdx.x;
    const int cg = bid & 63;          // column group
    const int fl = bid >> 6;          // local field
    const int f  = fl & 1;
    const int b  = b0 + (fl >> 1);
    const int c0 = cg * NC;

    // --- stage in 8 columns: 2048 float4 loads (64B contiguous per row) ---
    const float4* src4 = (const float4*)(fields + (size_t)fl * HH * WW + c0);
#pragma unroll
    for (int k = 0; k < 8; ++k) {
        int p  = tid + 256 * k;       // float4 index 0..2047
        int i  = p >> 2;              // row
        int jj = p & 3;               // float4 within row segment (2 columns)
        float4 v = src4[(size_t)i * (WW / 2) + jj];
        bufA[(2 * jj)     * 512 + i] = make_float2(v.x, v.y);
        bufA[(2 * jj + 1) * 512 + i] = make_float2(v.z, v.w);
    }
    __syncthreads();

    // --- 8 parallel FFTs: group g handles column c0+g with 32 threads ---
    const int g = tid >> 5;
    const int l = tid & 31;
    const int c = c0 + g;
    float2* sp = bufA + g * 512;
    float2* dp = bufB + g * 512;
    for (int s = 0; s < 8; ++s) {     // stages 0..7 (stage 8 fused below)
        const int m = 1 << s;
#pragma unroll
        for (int u = 0; u < 8; ++u) {
            int k = l + 32 * u;       // 0..255
            int j = k >> s;
            float2 c0v = sp[k];
            float2 c1v = sp[k + 256];
            float sx = c0v.x + c1v.x, sy = c0v.y + c1v.y;
            float dx = c0v.x - c1v.x, dy = c0v.y - c1v.y;
            float ang = -3.14159265358979323846f * (float)j / (float)(256 >> s);
            float sn, cs;
            __sincosf(ang, &sn, &cs);
            int idx = k + (j << s);
            dp[idx]     = make_float2(sx, sy);
            dp[idx + m] = make_float2(cs * dx - sn * dy, cs * dy + sn * dx);
        }
        __syncthreads();
        float2* tmp = sp; sp = dp; dp = tmp;
    }
    // after 8 swaps sp == bufA (holds stage-7 output); bufB is dead -> hist
    float* hist = (float*)bufB;
    hist[tid] = 0.f;
    hist[tid + 256] = 0.f;
    __syncthreads();

    // --- stage 8 (twiddle = 1) fused with |X|^2 + radial binning ---
    const float fc  = (float)(c - 256) * (1.0f / 256.0f);
    const float fc2 = fc * fc;
#pragma unroll
    for (int u = 0; u < 8; ++u) {
        int k = l + 32 * u;
        float2 c0v = sp[k];
        float2 c1v = sp[k + 256];
        float sx = c0v.x + c1v.x, sy = c0v.y + c1v.y;
        float dx = c0v.x - c1v.x, dy = c0v.y - c1v.y;
        float m0 = sx * sx + sy * sy;     // output row k
        float m1 = dx * dx + dy * dy;     // output row k + 256
        float fr0 = (float)(k - 256) * (1.0f / 256.0f);
        float fr1 = (float)(k)       * (1.0f / 256.0f);  // (k+256-256)/256
        float e0 = fr0 * fr0 + fc2;       // exact in fp32 (<= 18-bit ints /2^16)
        float e1 = fr1 * fr1 + fc2;
        int b0i = min((int)(sqrt((double)e0) * 511.0), 511);
        int b1i = min((int)(sqrt((double)e1) * 511.0), 511);
        atomicAdd(&hist[b0i], m0);
        atomicAdd(&hist[b1i], m1);
    }
    __syncthreads();

    float* gb = bins + ((size_t)f * NBATCH + b) * NBINS;
    atomicAdd(&gb[tid],       hist[tid]);
    atomicAdd(&gb[tid + 256], hist[tid + 256]);
}

// ---------------------------------------------------------------------------
// Final: loss = mean_b sum_{k<511} es[b][k] / max(ns[b][k], 1e-8)
// ---------------------------------------------------------------------------
__global__ void loss_kernel(const float* __restrict__ bins,
                            float* __restrict__ outp) {
    __shared__ float red[256];
    const int tid = threadIdx.x;
    float acc = 0.f;
    for (int b = 0; b < NBATCH; ++b) {
        const float* ns = bins + (size_t)b * NBINS;             // f = 0 (t)
        const float* es = bins + (size_t)(NBATCH + b) * NBINS;  // f = 1 (z-t)
        for (int k = tid; k < 511; k += 256)
            acc += es[k] / fmaxf(ns[k], 1e-8f);
    }
    red[tid] = acc;
    __syncthreads();
    for (int s = 128; s > 0; s >>= 1) {
        if (tid < s) red[tid] += red[tid + s];
        __syncthreads();
    }
    if (tid == 0) outp[0] = red[0] / (float)NBATCH;
}

// ---------------------------------------------------------------------------
extern "C" void kernel_launch(void* const* d_in, const int* in_sizes, int n_in,
                              void* d_out, int out_size, void* d_ws, size_t ws_size,
                              hipStream_t stream) {
    const float2* z = (const float2*)d_in[0];
    const float2* t = (const float2*)d_in[1];
    float* outp = (float*)d_out;

    const size_t binsBytes = (size_t)2 * NBATCH * NBINS * sizeof(float);  // 64 KiB
    const size_t fpb = (size_t)2 * HH * WW * sizeof(float2);  // 4 MiB / batch (2 fields)

    // Largest power-of-two batch chunk that fits the workspace.
    int CB = 16;
    while (CB > 1 && binsBytes + (size_t)CB * fpb > ws_size) CB >>= 1;

    float*  bins   = (float*)d_ws;
    float2* fields = (float2*)((char*)d_ws + binsBytes);

    hipMemsetAsync(bins, 0, binsBytes, stream);

    for (int b0 = 0; b0 < NBATCH; b0 += CB) {
        row_fft_kernel<<<CB * 512, 256, 0, stream>>>(
            (const float4*)z, (const float4*)t, fields, b0);
        col_fft_bin_kernel<<<CB * 2 * 64, 256, 0, stream>>>(fields, bins, b0);
    }
    loss_kernel<<<1, 256, 0, stream>>>(bins, outp);
}

// Round 3
// 179.556 us; speedup vs baseline: 1.9250x; 1.2281x over previous
//
#include <hip/hip_runtime.h>

#define HH 512
#define WW 512
#define NBATCH 16
#define NBINS 512   // 511 real shells + 1 overflow (dropped)
#define NCG 64      // column groups of 8 columns

#define PI_F 3.14159265358979323846f

// XOR swizzle on float2 index within a 512-element column: keeps every
// access phase (write 8i+r, read i+64u, write (i&7)+64(i>>3)+8r) at the
// conflict-free b64 baseline of 4 lanes per bank-pair.
#define SW(r) ((r) ^ (((r) >> 4) & 0xF))

__device__ __forceinline__ float2 cadd(float2 a, float2 b){ return make_float2(a.x+b.x, a.y+b.y); }
__device__ __forceinline__ float2 csub(float2 a, float2 b){ return make_float2(a.x-b.x, a.y-b.y); }
__device__ __forceinline__ float2 cmul(float2 a, float2 b){
    return make_float2(a.x*b.x - a.y*b.y, a.x*b.y + a.y*b.x);
}

// 8-point DFT, y_r = sum_u a_u * w8^{ru} (forward, w8 = exp(-i pi/4)).
__device__ __forceinline__ void dft8(const float2* a, float2* y) {
    const float s2 = 0.70710678118654752440f;
    float2 t02a = cadd(a[0], a[4]), t02s = csub(a[0], a[4]);
    float2 t13a = cadd(a[2], a[6]), t13s = csub(a[2], a[6]);
    float2 E0 = cadd(t02a, t13a);
    float2 E2 = csub(t02a, t13a);
    float2 E1 = make_float2(t02s.x + t13s.y, t02s.y - t13s.x);  // t02s - i*t13s
    float2 E3 = make_float2(t02s.x - t13s.y, t02s.y + t13s.x);  // t02s + i*t13s
    float2 u02a = cadd(a[1], a[5]), u02s = csub(a[1], a[5]);
    float2 u13a = cadd(a[3], a[7]), u13s = csub(a[3], a[7]);
    float2 O0 = cadd(u02a, u13a);
    float2 O2 = csub(u02a, u13a);
    float2 O1 = make_float2(u02s.x + u13s.y, u02s.y - u13s.x);
    float2 O3 = make_float2(u02s.x - u13s.y, u02s.y + u13s.x);
    float2 wO1 = make_float2(s2 * (O1.x + O1.y), s2 * (O1.y - O1.x));  // w8^1*O1
    float2 wO2 = make_float2(O2.y, -O2.x);                             // -i*O2
    float2 wO3 = make_float2(s2 * (O3.y - O3.x), -s2 * (O3.x + O3.y)); // w8^3*O3
    y[0] = cadd(E0, O0);  y[4] = csub(E0, O0);
    y[1] = cadd(E1, wO1); y[5] = csub(E1, wO1);
    y[2] = cadd(E2, wO2); y[6] = csub(E2, wO2);
    y[3] = cadd(E3, wO3); y[7] = csub(E3, wO3);
}

// w[r] = exp(i * base * r), r = 0..7 (base is negative for forward FFT).
__device__ __forceinline__ void twiddle8(float base, float2* w) {
    float s1, c1, s4, c4;
    __sincosf(base, &s1, &c1);
    __sincosf(4.0f * base, &s4, &c4);
    w[0] = make_float2(1.0f, 0.0f);
    w[1] = make_float2(c1, s1);
    w[2] = cmul(w[1], w[1]);
    w[3] = cmul(w[2], w[1]);
    w[4] = make_float2(c4, s4);
    w[5] = cmul(w[4], w[1]);
    w[6] = cmul(w[4], w[2]);
    w[7] = cmul(w[4], w[3]);
}

// Radix-8 Stockham, N=512: stage t has S=8^t; butterfly i (=lane):
// q=i%S, j=i/S; inputs src[i+64u]; dst[q + 8jS + rS] = y_r * w_512^{jSr}.
__device__ __forceinline__ void fft512_stage0_store(float2* rb, int lane, const float2* a) {
    float2 y[8]; dft8(a, y);
    float2 w[8]; twiddle8(-PI_F * (float)lane * (1.0f / 256.0f), w);
#pragma unroll
    for (int r = 0; r < 8; ++r) rb[SW(8 * lane + r)] = cmul(y[r], w[r]);
}

__device__ __forceinline__ void fft512_stage1(float2* rb, int lane) {
    float2 a[8];
#pragma unroll
    for (int u = 0; u < 8; ++u) a[u] = rb[SW(lane + 64 * u)];
    float2 y[8]; dft8(a, y);
    float2 w[8]; twiddle8(-PI_F * (float)(lane >> 3) * (1.0f / 32.0f), w);
    const int qb = (lane & 7) + ((lane >> 3) << 6);
#pragma unroll
    for (int r = 0; r < 8; ++r) rb[SW(qb + 8 * r)] = cmul(y[r], w[r]);
}

__device__ __forceinline__ void fft512_stage2(const float2* rb, int lane, float2* y) {
    float2 a[8];
#pragma unroll
    for (int u = 0; u < 8; ++u) a[u] = rb[SW(lane + 64 * u)];
    dft8(a, y);   // S=64: j=0, twiddles = 1; y[r] = X[lane + 64r] (natural order)
}

// ---------------------------------------------------------------------------
// Row pass: block = 256 threads = 4 waves; wave g: field f=g&1 (t or z-t),
// row h0+(g>>1). Direct coalesced global loads into stage-0 registers,
// 2 wave-local LDS exchanges (no __syncthreads anywhere), natural-order
// coalesced stores. grid = CB*256.
// ---------------------------------------------------------------------------
__global__ __launch_bounds__(256, 4)
void row_fft_kernel(const float2* __restrict__ z, const float2* __restrict__ t,
                    float2* __restrict__ fields, int b0) {
    __shared__ float2 buf[4 * 512];   // 16 KiB, one 512-col region per wave
    const int tid  = threadIdx.x;
    const int lane = tid & 63;
    const int g    = tid >> 6;
    const int bid  = blockIdx.x;
    const int lb   = bid >> 8;
    const int h    = ((bid & 255) << 1) | (g >> 1);
    const int f    = g & 1;
    const int b    = b0 + lb;
    const size_t rowOff = ((size_t)(b * HH + h)) * WW;

    float2 a[8];
    if (f == 0) {
        const float2* tr = t + rowOff;
#pragma unroll
        for (int u = 0; u < 8; ++u) a[u] = tr[lane + 64 * u];
    } else {
        const float2* tr = t + rowOff;
        const float2* zr = z + rowOff;
#pragma unroll
        for (int u = 0; u < 8; ++u) {
            float2 tv = tr[lane + 64 * u];
            float2 zv = zr[lane + 64 * u];
            a[u] = make_float2(zv.x - tv.x, zv.y - tv.y);
        }
    }
    float2* rb = buf + (g << 9);
    fft512_stage0_store(rb, lane, a);
    __builtin_amdgcn_wave_barrier();
    fft512_stage1(rb, lane);
    __builtin_amdgcn_wave_barrier();
    float2 y[8];
    fft512_stage2(rb, lane, y);

    float2* orow = fields + ((size_t)(lb * 2 + f) * HH + h) * WW;
#pragma unroll
    for (int r = 0; r < 8; ++r) orow[lane + 64 * r] = y[r];
}

// ---------------------------------------------------------------------------
// Column pass: block = 512 threads = 8 waves; wave g owns column c0+g.
// Coalesced 64B row-segment staging into swizzled LDS, radix-8 FFT
// (wave-local exchanges), stage 2 fused with |X|^2 + radial binning into an
// LDS histogram, flushed as a non-atomic per-block partial. grid = CB*2*64.
// ---------------------------------------------------------------------------
__global__ __launch_bounds__(512, 4)
void col_fft_bin_kernel(const float2* __restrict__ fields,
                        float* __restrict__ partials, int b0) {
    __shared__ float2 colBuf[8 * 512];   // 32 KiB
    __shared__ float hist[NBINS];        // 2 KiB
    const int tid  = threadIdx.x;
    const int lane = tid & 63;
    const int g    = tid >> 6;
    const int bid  = blockIdx.x;
    const int cg   = bid & 63;
    const int fl   = bid >> 6;
    const int f    = fl & 1;
    const int b    = b0 + (fl >> 1);
    const int c0   = cg << 3;

    // stage in 8 columns: 2048 float4 (64 B contiguous per row segment)
    const float4* src4 = (const float4*)(fields + (size_t)fl * (HH * WW) + c0);
#pragma unroll
    for (int k = 0; k < 4; ++k) {
        int p  = tid + (k << 9);
        int i  = p >> 2;            // row
        int jj = p & 3;             // float4 within segment (2 columns)
        float4 v = src4[(size_t)i * (WW / 2) + jj];
        colBuf[((2 * jj)     << 9) + SW(i)] = make_float2(v.x, v.y);
        colBuf[((2 * jj + 1) << 9) + SW(i)] = make_float2(v.z, v.w);
    }
    hist[tid] = 0.0f;   // 512 threads == NBINS
    __syncthreads();

    float2* rb = colBuf + (g << 9);
    {
        float2 a[8];
#pragma unroll
        for (int u = 0; u < 8; ++u) a[u] = rb[SW(lane + 64 * u)];
        fft512_stage0_store(rb, lane, a);
    }
    __builtin_amdgcn_wave_barrier();
    fft512_stage1(rb, lane);
    __builtin_amdgcn_wave_barrier();
    float2 y[8];
    fft512_stage2(rb, lane, y);

    // fused |X|^2 + radial shell binning (output row k = lane+64r, col c)
    const int c = c0 + g;
    const float fcv = (float)(c - 256) * (1.0f / 256.0f);
    const float fc2 = fcv * fcv;
#pragma unroll
    for (int r = 0; r < 8; ++r) {
        int k = lane + (r << 6);
        float fr = (float)(k - 256) * (1.0f / 256.0f);
        float e = fr * fr + fc2;                       // exact in fp32
        int bin = min((int)(sqrt((double)e) * 511.0), 511);
        float mag = y[r].x * y[r].x + y[r].y * y[r].y;
        atomicAdd(&hist[bin], mag);
    }
    __syncthreads();

    partials[(((size_t)f * NBATCH + b) * NCG + cg) * NBINS + tid] = hist[tid];
}

// ---------------------------------------------------------------------------
// Loss: one block per batch; reduce 64 column-group partials per (f,b),
// then sum es/max(ns,1e-8) over shells 0..510, atomicAdd the batch mean.
// ---------------------------------------------------------------------------
__global__ __launch_bounds__(512)
void loss_kernel(const float* __restrict__ partials, float* __restrict__ outp) {
    __shared__ float red[512];
    const int b = blockIdx.x;
    const int tid = threadIdx.x;
    float ns = 0.0f, es = 0.0f;
    const float* pn = partials + ((size_t)(0 * NBATCH + b) * NCG) * NBINS + tid;
    const float* pe = partials + ((size_t)(1 * NBATCH + b) * NCG) * NBINS + tid;
#pragma unroll 4
    for (int cgi = 0; cgi < NCG; ++cgi) {
        ns += pn[cgi * NBINS];
        es += pe[cgi * NBINS];
    }
    red[tid] = (tid < 511) ? es / fmaxf(ns, 1e-8f) : 0.0f;
    __syncthreads();
    for (int s = 256; s > 0; s >>= 1) {
        if (tid < s) red[tid] += red[tid + s];
        __syncthreads();
    }
    if (tid == 0) atomicAdd(outp, red[0] * (1.0f / NBATCH));
}

// ---------------------------------------------------------------------------
extern "C" void kernel_launch(void* const* d_in, const int* in_sizes, int n_in,
                              void* d_out, int out_size, void* d_ws, size_t ws_size,
                              hipStream_t stream) {
    const float2* z = (const float2*)d_in[0];
    const float2* t = (const float2*)d_in[1];
    float* outp = (float*)d_out;

    const size_t partBytes = (size_t)2 * NBATCH * NCG * NBINS * sizeof(float); // 4 MiB
    const size_t fpb = (size_t)2 * HH * WW * sizeof(float2);                   // 4 MiB/batch

    int CB = 16;
    while (CB > 1 && partBytes + (size_t)CB * fpb > ws_size) CB >>= 1;

    float*  partials = (float*)d_ws;
    float2* fields   = (float2*)((char*)d_ws + partBytes);

    hipMemsetAsync(outp, 0, sizeof(float), stream);

    for (int b0 = 0; b0 < NBATCH; b0 += CB) {
        row_fft_kernel<<<CB * 256, 256, 0, stream>>>(z, t, fields, b0);
        col_fft_bin_kernel<<<CB * 2 * 64, 512, 0, stream>>>(fields, partials, b0);
    }
    loss_kernel<<<NBATCH, 512, 0, stream>>>(partials, outp);
}

// Round 4
// 158.181 us; speedup vs baseline: 2.1851x; 1.1351x over previous
//
#include <hip/hip_runtime.h>

#define HH 512
#define WW 512
#define NBATCH 16
#define NBINS 512   // 511 real shells + 1 overflow (never accumulated)

#define PI_F 3.14159265358979323846f

// Swizzle for the per-wave FFT exchange region (512 float2): keeps all three
// access phases at the conflict-free b64 baseline (verified R3, absmax 0).
#define SW(r) ((r) ^ (((r) >> 4) & 0xF))
// Swizzle for the 512x8 transpose tile: A = 8c + (hh ^ ((c>>1)&7)).
// Write phase (c consecutive, hh fixed) and read phase (8 c x 8 hh per wave)
// both give exactly 4 lanes per bank-pair -> conflict-free b64.
#define TSW(c, hh) (((c) << 3) + ((hh) ^ (((c) >> 1) & 7)))

__device__ __forceinline__ float2 cadd(float2 a, float2 b){ return make_float2(a.x+b.x, a.y+b.y); }
__device__ __forceinline__ float2 csub(float2 a, float2 b){ return make_float2(a.x-b.x, a.y-b.y); }
__device__ __forceinline__ float2 cmul(float2 a, float2 b){
    return make_float2(a.x*b.x - a.y*b.y, a.x*b.y + a.y*b.x);
}

// 8-point DFT, y_r = sum_u a_u * w8^{ru} (forward, w8 = exp(-i pi/4)).
__device__ __forceinline__ void dft8(const float2* a, float2* y) {
    const float s2 = 0.70710678118654752440f;
    float2 t02a = cadd(a[0], a[4]), t02s = csub(a[0], a[4]);
    float2 t13a = cadd(a[2], a[6]), t13s = csub(a[2], a[6]);
    float2 E0 = cadd(t02a, t13a);
    float2 E2 = csub(t02a, t13a);
    float2 E1 = make_float2(t02s.x + t13s.y, t02s.y - t13s.x);
    float2 E3 = make_float2(t02s.x - t13s.y, t02s.y + t13s.x);
    float2 u02a = cadd(a[1], a[5]), u02s = csub(a[1], a[5]);
    float2 u13a = cadd(a[3], a[7]), u13s = csub(a[3], a[7]);
    float2 O0 = cadd(u02a, u13a);
    float2 O2 = csub(u02a, u13a);
    float2 O1 = make_float2(u02s.x + u13s.y, u02s.y - u13s.x);
    float2 O3 = make_float2(u02s.x - u13s.y, u02s.y + u13s.x);
    float2 wO1 = make_float2(s2 * (O1.x + O1.y), s2 * (O1.y - O1.x));
    float2 wO2 = make_float2(O2.y, -O2.x);
    float2 wO3 = make_float2(s2 * (O3.y - O3.x), -s2 * (O3.x + O3.y));
    y[0] = cadd(E0, O0);  y[4] = csub(E0, O0);
    y[1] = cadd(E1, wO1); y[5] = csub(E1, wO1);
    y[2] = cadd(E2, wO2); y[6] = csub(E2, wO2);
    y[3] = cadd(E3, wO3); y[7] = csub(E3, wO3);
}

__device__ __forceinline__ void twiddle8(float base, float2* w) {
    float s1, c1, s4, c4;
    __sincosf(base, &s1, &c1);
    __sincosf(4.0f * base, &s4, &c4);
    w[0] = make_float2(1.0f, 0.0f);
    w[1] = make_float2(c1, s1);
    w[2] = cmul(w[1], w[1]);
    w[3] = cmul(w[2], w[1]);
    w[4] = make_float2(c4, s4);
    w[5] = cmul(w[4], w[1]);
    w[6] = cmul(w[4], w[2]);
    w[7] = cmul(w[4], w[3]);
}

// Radix-8 Stockham, N=512 (verified R3): 2 LDS round trips, wave-local.
__device__ __forceinline__ void fft512_stage0_store(float2* rb, int lane, const float2* a) {
    float2 y[8]; dft8(a, y);
    float2 w[8]; twiddle8(-PI_F * (float)lane * (1.0f / 256.0f), w);
#pragma unroll
    for (int r = 0; r < 8; ++r) rb[SW(8 * lane + r)] = cmul(y[r], w[r]);
}

__device__ __forceinline__ void fft512_stage1(float2* rb, int lane) {
    float2 a[8];
#pragma unroll
    for (int u = 0; u < 8; ++u) a[u] = rb[SW(lane + 64 * u)];
    float2 y[8]; dft8(a, y);
    float2 w[8]; twiddle8(-PI_F * (float)(lane >> 3) * (1.0f / 32.0f), w);
    const int qb = (lane & 7) + ((lane >> 3) << 6);
#pragma unroll
    for (int r = 0; r < 8; ++r) rb[SW(qb + 8 * r)] = cmul(y[r], w[r]);
}

__device__ __forceinline__ void fft512_stage2(const float2* rb, int lane, float2* y) {
    float2 a[8];
#pragma unroll
    for (int u = 0; u < 8; ++u) a[u] = rb[SW(lane + 64 * u)];
    dft8(a, y);   // twiddle-free; y[r] = X[lane + 64r] (natural order)
}

// ---------------------------------------------------------------------------
// Row pass: block = 512 thr = 8 waves; wave g owns row h0+g of batch b, BOTH
// fields (t loaded once). FFT each field, transpose the 8-row x 512-col tile
// in LDS, store fieldsT[field][col][row] as coalesced 64B column segments.
// grid = CB*64.
// ---------------------------------------------------------------------------
__global__ __launch_bounds__(512, 4)
void row_fft_kernel(const float2* __restrict__ z, const float2* __restrict__ t,
                    float2* __restrict__ fieldsT, int b0) {
    __shared__ float2 buf[8 * 512];   // 32 KiB: FFT regions, then transpose tile
    const int tid  = threadIdx.x;
    const int lane = tid & 63;
    const int g    = tid >> 6;
    const int bid  = blockIdx.x;
    const int hg   = bid & 63;
    const int lb   = bid >> 6;
    const int b    = b0 + lb;
    const int h    = (hg << 3) | g;
    const size_t rowOff = ((size_t)(b * HH + h)) * WW;

    const float2* tr = t + rowOff;
    const float2* zr = z + rowOff;
    float2 tv[8], zv[8];
#pragma unroll
    for (int u = 0; u < 8; ++u) tv[u] = tr[lane + 64 * u];
#pragma unroll
    for (int u = 0; u < 8; ++u) zv[u] = zr[lane + 64 * u];

    float2* rb = buf + (g << 9);
#pragma unroll
    for (int f = 0; f < 2; ++f) {
        float2 a[8];
        if (f == 0) {
#pragma unroll
            for (int u = 0; u < 8; ++u) a[u] = tv[u];
        } else {
#pragma unroll
            for (int u = 0; u < 8; ++u) a[u] = make_float2(zv[u].x - tv[u].x,
                                                           zv[u].y - tv[u].y);
        }
        fft512_stage0_store(rb, lane, a);
        __builtin_amdgcn_wave_barrier();
        fft512_stage1(rb, lane);
        __builtin_amdgcn_wave_barrier();
        float2 y[8];
        fft512_stage2(rb, lane, y);

        __syncthreads();   // all waves done reading their FFT regions
        // transpose tile: (col c, row-in-tile hh=g)
#pragma unroll
        for (int r = 0; r < 8; ++r) {
            int c = lane + (r << 6);
            buf[TSW(c, g)] = y[r];
        }
        __syncthreads();
        // coalesced store: per wave-instr 8 cols x 8 rows = 8 x 64B segments
        float2* outF = fieldsT + ((size_t)(lb * 2 + f) << 18);  // * 512*512
#pragma unroll
        for (int k = 0; k < 8; ++k) {
            int e  = tid + (k << 9);
            int c  = e >> 3;
            int hh = e & 7;
            outF[((size_t)c << 9) + (hg << 3) + hh] = buf[TSW(c, hh)];
        }
        __syncthreads();   // tile region free before next field's stage 0
    }
}

// ---------------------------------------------------------------------------
// Column pass: block = 512 thr = 8 waves; wave g owns column cg*8+g. Loads
// its column CONTIGUOUSLY from fieldsT straight into registers (no staging
// LDS, no staging barrier), wave-local FFT, fused |X|^2 + shell binning with
// overflow pixels (e >= 1, dropped by the loss) skipped entirely. One
// barrier pair around the shared histogram; global-atomic flush into bins.
// grid = CB*2*64.
// ---------------------------------------------------------------------------
__global__ __launch_bounds__(512, 4)
void col_fft_bin_kernel(const float2* __restrict__ fieldsT,
                        float* __restrict__ bins, int b0) {
    __shared__ float2 buf[8 * 512];   // 32 KiB FFT exchange regions
    __shared__ float hist[NBINS];
    const int tid  = threadIdx.x;
    const int lane = tid & 63;
    const int g    = tid >> 6;
    const int bid  = blockIdx.x;
    const int cg   = bid & 63;
    const int fl   = bid >> 6;
    const int f    = fl & 1;
    const int b    = b0 + (fl >> 1);
    const int c    = (cg << 3) | g;

    hist[tid] = 0.0f;                 // 512 threads == NBINS
    __syncthreads();

    const float2* colT = fieldsT + (((size_t)fl << 9) + c) * 512;
    float2 a[8];
#pragma unroll
    for (int u = 0; u < 8; ++u) a[u] = colT[lane + (u << 6)];

    float2* rb = buf + (g << 9);
    fft512_stage0_store(rb, lane, a);
    __builtin_amdgcn_wave_barrier();
    fft512_stage1(rb, lane);
    __builtin_amdgcn_wave_barrier();
    float2 y[8];
    fft512_stage2(rb, lane, y);

    const float fcv = (float)(c - 256) * (1.0f / 256.0f);
    const float fc2 = fcv * fcv;
#pragma unroll
    for (int r = 0; r < 8; ++r) {
        int k = lane + (r << 6);
        float fr = (float)(k - 256) * (1.0f / 256.0f);
        float e = fr * fr + fc2;                   // exact in fp32
        if (e < 1.0f) {                            // overflow shell dropped
            int bin = (int)(sqrt((double)e) * 511.0);   // <= 510 guaranteed
            atomicAdd(&hist[bin], y[r].x * y[r].x + y[r].y * y[r].y);
        }
    }
    __syncthreads();
    atomicAdd(&bins[((size_t)f * NBATCH + b) * NBINS + tid], hist[tid]);
}

// ---------------------------------------------------------------------------
// Loss: single block reads the 64 KiB bins array.
// loss = mean_b sum_{k<511} es[b][k] / max(ns[b][k], 1e-8)
// ---------------------------------------------------------------------------
__global__ __launch_bounds__(512)
void loss_kernel(const float* __restrict__ bins, float* __restrict__ outp) {
    __shared__ float red[512];
    const int tid = threadIdx.x;
    float acc = 0.0f;
    if (tid < 511) {
#pragma unroll 4
        for (int b = 0; b < NBATCH; ++b) {
            float ns = bins[((size_t)b) * NBINS + tid];
            float es = bins[((size_t)(NBATCH + b)) * NBINS + tid];
            acc += es / fmaxf(ns, 1e-8f);
        }
    }
    red[tid] = acc;
    __syncthreads();
    for (int s = 256; s > 0; s >>= 1) {
        if (tid < s) red[tid] += red[tid + s];
        __syncthreads();
    }
    if (tid == 0) outp[0] = red[0] * (1.0f / NBATCH);
}

// ---------------------------------------------------------------------------
extern "C" void kernel_launch(void* const* d_in, const int* in_sizes, int n_in,
                              void* d_out, int out_size, void* d_ws, size_t ws_size,
                              hipStream_t stream) {
    const float2* z = (const float2*)d_in[0];
    const float2* t = (const float2*)d_in[1];
    float* outp = (float*)d_out;

    const size_t binsBytes = (size_t)2 * NBATCH * NBINS * sizeof(float);  // 64 KiB
    const size_t fpb = (size_t)2 * HH * WW * sizeof(float2);              // 4 MiB/batch

    int CB = 16;
    while (CB > 1 && binsBytes + (size_t)CB * fpb > ws_size) CB >>= 1;

    float*  bins    = (float*)d_ws;
    float2* fieldsT = (float2*)((char*)d_ws + binsBytes);

    hipMemsetAsync(bins, 0, binsBytes, stream);

    for (int b0 = 0; b0 < NBATCH; b0 += CB) {
        row_fft_kernel<<<CB * 64, 512, 0, stream>>>(z, t, fieldsT, b0);
        col_fft_bin_kernel<<<CB * 2 * 64, 512, 0, stream>>>(fieldsT, bins, b0);
    }
    loss_kernel<<<1, 512, 0, stream>>>(bins, outp);
}